// Round 4
// baseline (334.734 us; speedup 1.0000x reference)
//
#include <hip/hip_runtime.h>
#include <math.h>

// NeRF volume rendering: N=65536 rays, S=192 samples.
// v5 = v4 with native clang vectors (ext_vector_type) so
// __builtin_nontemporal_store accepts the pointer (HIP float4 is a class ->
// rejected; v4 failed to compile). Vectorization theory still untested.
//
// Theory (from v1/v2 counters: HBM 29% of peak, VALU 25%, occ 68%, zero LDS
// conflicts): the kernel is request-rate-limited on dword-granular VMEM.
// Fix: lane l (l<48) owns 4 CONSECUTIVE samples so every bulk access is
// global_{load,store}_dwordx4 (16B/lane):
//   - 5 fat loads (z, sigma, 3x rgb) + 3 fat NT stores per wave
//     (vs ~29 dword-granular ops before).
//   - one 64-lane DPP scan per ray (local 3-mul prefix first); no carry chain.
//   - neighbor z via one wave_shl1 DPP instead of a second z load.
//   - nontemporal stores for the 150MB weights/trans/alpha streams.
// Lanes 48-63: no I/O; sigma=0 -> alpha=0, om=1 -> neutral in scan/reduce.

constexpr int kRays = 65536;
constexpr int kS = 192;

typedef float v4f __attribute__((ext_vector_type(4)));

// ---- DPP cross-lane helpers ----
template <int CTRL, int RMASK>
__device__ __forceinline__ float dpp_mul(float v) {
    const int t = __builtin_amdgcn_update_dpp(0x3f800000 /*1.0f*/, __float_as_int(v),
                                              CTRL, RMASK, 0xF, false);
    return v * __int_as_float(t);
}
template <int CTRL, int RMASK>
__device__ __forceinline__ float dpp_add(float v) {
    const int t = __builtin_amdgcn_update_dpp(0 /*0.0f*/, __float_as_int(v),
                                              CTRL, RMASK, 0xF, false);
    return v + __int_as_float(t);
}

// Inclusive 64-lane prefix product (order matters: shifts THEN broadcasts).
__device__ __forceinline__ float scan_mul64(float x) {
    float v = x;
    v = dpp_mul<0x111, 0xF>(v);   // row_shr:1
    v = dpp_mul<0x112, 0xF>(v);   // row_shr:2
    v = dpp_mul<0x114, 0xF>(v);   // row_shr:4
    v = dpp_mul<0x118, 0xF>(v);   // row_shr:8
    v = dpp_mul<0x142, 0xA>(v);   // row_bcast15 (rows 1,3)
    v = dpp_mul<0x143, 0xC>(v);   // row_bcast31 (rows 2,3)
    return v;
}

// 64-lane sum; total lands in lane 63. Same ordered ladder as the scan.
__device__ __forceinline__ float red_add64(float x) {
    float v = x;
    v = dpp_add<0x111, 0xF>(v);   // row_shr:1
    v = dpp_add<0x112, 0xF>(v);   // row_shr:2
    v = dpp_add<0x114, 0xF>(v);   // row_shr:4
    v = dpp_add<0x118, 0xF>(v);   // row_shr:8
    v = dpp_add<0x142, 0xA>(v);   // row_bcast15 (rows 1,3)
    v = dpp_add<0x143, 0xC>(v);   // row_bcast31 (rows 2,3)
    return v;
}

// wave_shr:1 -> lane i gets lane i-1; lane 0 gets `fill`.
__device__ __forceinline__ float wave_shr1(float x, float fill) {
    const int t = __builtin_amdgcn_update_dpp(__float_as_int(fill), __float_as_int(x),
                                              0x138, 0xF, 0xF, false);
    return __int_as_float(t);
}
// wave_shl:1 -> lane i gets lane i+1; lane 63 gets `fill`.
__device__ __forceinline__ float wave_shl1(float x, float fill) {
    const int t = __builtin_amdgcn_update_dpp(__float_as_int(fill), __float_as_int(x),
                                              0x130, 0xF, 0xF, false);
    return __int_as_float(t);
}

__global__ __launch_bounds__(256) void nerf_render_kernel(
    const float* __restrict__ rgb,      // [N, S, 3]
    const float* __restrict__ sigma,    // [N, S]
    const float* __restrict__ z_vals,   // [N, S]
    const float* __restrict__ rays_d,   // [N, 3]
    float* __restrict__ out)
{
    const int lane = threadIdx.x & 63;
    const int ray  = (blockIdx.x << 2) + (threadIdx.x >> 6);  // 4 waves/block

    float* __restrict__ rgb_map   = out;                                        // [N,3]
    float* __restrict__ depth_map = out + (size_t)kRays * 3;                    // [N]
    float* __restrict__ acc_map   = out + (size_t)kRays * 4;                    // [N]
    float* __restrict__ weights_o = out + (size_t)kRays * 5;                    // [N,S]
    float* __restrict__ disp_map  = out + (size_t)kRays * 5 + (size_t)kRays * kS;      // [N]
    float* __restrict__ trans_o   = out + (size_t)kRays * 6 + (size_t)kRays * kS;      // [N,S]
    float* __restrict__ alpha_o   = out + (size_t)kRays * 6 + (size_t)kRays * kS * 2;  // [N,S]

    const float dx = rays_d[ray * 3 + 0];
    const float dy = rays_d[ray * 3 + 1];
    const float dz = rays_d[ray * 3 + 2];
    const float nrm = sqrtf(dx * dx + dy * dy + dz * dz);

    const size_t base = (size_t)ray * kS;
    const bool act = lane < 48;            // 48 lanes x 4 samples = 192

    // ---- fat loads: 5 x global_load_dwordx4 per wave ----
    v4f zq = (v4f)(0.f), sq = (v4f)(0.f);
    v4f c0 = (v4f)(0.f), c1 = (v4f)(0.f), c2 = (v4f)(0.f);
    if (act) {
        zq = *reinterpret_cast<const v4f*>(z_vals + base + 4 * lane);
        sq = *reinterpret_cast<const v4f*>(sigma  + base + 4 * lane);
        const float* rp = rgb + base * 3 + 12 * lane;   // 16B-aligned (48B stride)
        c0 = *reinterpret_cast<const v4f*>(rp);
        c1 = *reinterpret_cast<const v4f*>(rp + 4);
        c2 = *reinterpret_cast<const v4f*>(rp + 8);
    }

    // neighbor's first z (for element 3's dist); lane 47 uses 1e10 instead
    const float znext = wave_shl1(zq[0], 0.f);

    const float zv[4] = {zq[0], zq[1], zq[2], zq[3]};
    const float sv[4] = {sq[0], sq[1], sq[2], sq[3]};
    const float rv[4] = {c0[0], c0[3], c1[2], c2[1]};
    const float gv[4] = {c0[1], c1[0], c1[3], c2[2]};
    const float bv[4] = {c0[2], c1[1], c2[0], c2[3]};

    float alpha[4], om[4];
    #pragma unroll
    for (int j = 0; j < 4; ++j) {
        const int idx = 4 * lane + j;
        float d;
        if (j < 3)              d = zv[j + 1] - zv[j];
        else if (idx < kS - 1)  d = znext - zv[3];
        else                    d = 1e10f;          // last sample (and idle lanes)
        const float dist = d * nrm;
        const float s = sv[j] > 0.f ? sv[j] : 0.f;  // relu; idle lanes: s=0 -> alpha=0
        const float e = expf(-s * dist);
        alpha[j] = 1.0f - e;
        om[j]    = 1.0f - alpha[j];                 // match reference rounding
    }

    // ---- local inclusive prefix products, then ONE cross-lane scan ----
    const float q0 = om[0];
    const float q1 = q0 * om[1];
    const float q2 = q1 * om[2];
    const float q3 = q2 * om[3];
    const float incl = scan_mul64(q3);              // idle lanes contribute 1.0
    const float excl = wave_shr1(incl, 1.0f);       // exclusive prefix across lanes

    const float trans[4] = {excl, excl * q0, excl * q1, excl * q2};
    float w[4];
    #pragma unroll
    for (int j = 0; j < 4; ++j) w[j] = alpha[j] * trans[j];

    // ---- fat stores: 3 x nontemporal global_store_dwordx4 per wave ----
    if (act) {
        const size_t o = base + 4 * lane;
        v4f tv = {trans[0], trans[1], trans[2], trans[3]};
        v4f av = {alpha[0], alpha[1], alpha[2], alpha[3]};
        v4f wv = {w[0], w[1], w[2], w[3]};
        __builtin_nontemporal_store(tv, reinterpret_cast<v4f*>(trans_o + o));
        __builtin_nontemporal_store(av, reinterpret_cast<v4f*>(alpha_o + o));
        __builtin_nontemporal_store(wv, reinterpret_cast<v4f*>(weights_o + o));
    }

    // ---- per-ray scalars: local 4-sum then one 64-lane DPP reduce each ----
    float sr = 0.f, sg_ = 0.f, sb = 0.f, sd = 0.f, sw = 0.f;
    #pragma unroll
    for (int j = 0; j < 4; ++j) {
        sr  += w[j] * rv[j];
        sg_ += w[j] * gv[j];
        sb  += w[j] * bv[j];
        sd  += w[j] * zv[j];
        sw  += w[j];
    }
    sr  = red_add64(sr);
    sg_ = red_add64(sg_);
    sb  = red_add64(sb);
    sd  = red_add64(sd);
    sw  = red_add64(sw);

    if (lane == 63) {
        rgb_map[ray * 3 + 0] = sr;
        rgb_map[ray * 3 + 1] = sg_;
        rgb_map[ray * 3 + 2] = sb;
        depth_map[ray] = sd;
        acc_map[ray]   = sw;
        const float q = fmaxf(1e-10f, sd / sw);
        disp_map[ray] = 1.0f / q;
    }
}

extern "C" void kernel_launch(void* const* d_in, const int* in_sizes, int n_in,
                              void* d_out, int out_size, void* d_ws, size_t ws_size,
                              hipStream_t stream) {
    const float* rgb    = (const float*)d_in[0];
    const float* sigma  = (const float*)d_in[1];
    const float* z_vals = (const float*)d_in[2];
    const float* rays_d = (const float*)d_in[3];
    float* out = (float*)d_out;

    const int blocks = kRays / 4;  // 4 rays (waves) per 256-thread block
    nerf_render_kernel<<<blocks, 256, 0, stream>>>(rgb, sigma, z_vals, rays_d, out);
}

// Round 5
// 329.853 us; speedup vs baseline: 1.0148x; 1.0148x over previous
//
#include <hip/hip_runtime.h>
#include <math.h>

// NeRF volume rendering: N=65536 rays, S=192 samples.
// v6: persistent-wave + register-prefetch restructure.
//
// History: v2 (DPP instead of shfl) NEUTRAL; v5 (all dwordx4 + NT stores)
// slightly WORSE (119->130us, 2.35->2.15 TB/s, byte counts identical).
// Three different instruction mixes all hit ~2.2-2.4 TB/s with VALU 23%,
// HBM 27%, occ 68% -> the wall is structural: 16384 short-lived blocks,
// each wave does ONE ray (one load->use chain, ~3.8KB in flight) and dies.
// Wave lifetime ~22k cy for ~1-2k cy of work = churn + unpipelined latency.
//
// v6: 2048 blocks x 4 waves; each wave streams 8 consecutive rays with a
// register double-buffer (ray r+1's 5 fat loads issued before processing
// ray r) -> loads stay in flight continuously. NT hint dropped (its A/B arm
// was the slower one). Math identical to v5 (passed, absmax 0.03125).

constexpr int kRays = 65536;
constexpr int kS = 192;
constexpr int kRaysPerWave = 8;
constexpr int kWavesPerBlock = 4;
constexpr int kBlocks = kRays / (kRaysPerWave * kWavesPerBlock);  // 2048

typedef float v4f __attribute__((ext_vector_type(4)));

// ---- DPP cross-lane helpers ----
template <int CTRL, int RMASK>
__device__ __forceinline__ float dpp_mul(float v) {
    const int t = __builtin_amdgcn_update_dpp(0x3f800000 /*1.0f*/, __float_as_int(v),
                                              CTRL, RMASK, 0xF, false);
    return v * __int_as_float(t);
}
template <int CTRL, int RMASK>
__device__ __forceinline__ float dpp_add(float v) {
    const int t = __builtin_amdgcn_update_dpp(0 /*0.0f*/, __float_as_int(v),
                                              CTRL, RMASK, 0xF, false);
    return v + __int_as_float(t);
}

// Inclusive 64-lane prefix product (shifts THEN broadcasts; order matters).
__device__ __forceinline__ float scan_mul64(float x) {
    float v = x;
    v = dpp_mul<0x111, 0xF>(v);   // row_shr:1
    v = dpp_mul<0x112, 0xF>(v);   // row_shr:2
    v = dpp_mul<0x114, 0xF>(v);   // row_shr:4
    v = dpp_mul<0x118, 0xF>(v);   // row_shr:8
    v = dpp_mul<0x142, 0xA>(v);   // row_bcast15 (rows 1,3)
    v = dpp_mul<0x143, 0xC>(v);   // row_bcast31 (rows 2,3)
    return v;
}

// 64-lane sum; total lands in lane 63.
__device__ __forceinline__ float red_add64(float x) {
    float v = x;
    v = dpp_add<0x111, 0xF>(v);
    v = dpp_add<0x112, 0xF>(v);
    v = dpp_add<0x114, 0xF>(v);
    v = dpp_add<0x118, 0xF>(v);
    v = dpp_add<0x142, 0xA>(v);
    v = dpp_add<0x143, 0xC>(v);
    return v;
}

// wave_shr:1 -> lane i gets lane i-1; lane 0 gets `fill`.
__device__ __forceinline__ float wave_shr1(float x, float fill) {
    const int t = __builtin_amdgcn_update_dpp(__float_as_int(fill), __float_as_int(x),
                                              0x138, 0xF, 0xF, false);
    return __int_as_float(t);
}
// wave_shl:1 -> lane i gets lane i+1; lane 63 gets `fill`.
__device__ __forceinline__ float wave_shl1(float x, float fill) {
    const int t = __builtin_amdgcn_update_dpp(__float_as_int(fill), __float_as_int(x),
                                              0x130, 0xF, 0xF, false);
    return __int_as_float(t);
}

struct RayRegs {
    v4f zq, sq, c0, c1, c2;   // z[4], sigma[4], rgb[12]
    float dx, dy, dz;         // ray direction
};

__global__ __launch_bounds__(256, 6) void nerf_render_kernel(
    const float* __restrict__ rgb,      // [N, S, 3]
    const float* __restrict__ sigma,    // [N, S]
    const float* __restrict__ z_vals,   // [N, S]
    const float* __restrict__ rays_d,   // [N, 3]
    float* __restrict__ out)
{
    const int lane = threadIdx.x & 63;
    const int wid  = blockIdx.x * kWavesPerBlock + (threadIdx.x >> 6);
    const int ray0 = wid * kRaysPerWave;     // 8 consecutive rays per wave
    const bool act = lane < 48;              // 48 lanes x 4 samples = 192

    float* __restrict__ rgb_map   = out;                                        // [N,3]
    float* __restrict__ depth_map = out + (size_t)kRays * 3;                    // [N]
    float* __restrict__ acc_map   = out + (size_t)kRays * 4;                    // [N]
    float* __restrict__ weights_o = out + (size_t)kRays * 5;                    // [N,S]
    float* __restrict__ disp_map  = out + (size_t)kRays * 5 + (size_t)kRays * kS;      // [N]
    float* __restrict__ trans_o   = out + (size_t)kRays * 6 + (size_t)kRays * kS;      // [N,S]
    float* __restrict__ alpha_o   = out + (size_t)kRays * 6 + (size_t)kRays * kS * 2;  // [N,S]

    auto load_ray = [&](int ray, RayRegs& R) {
        const size_t base = (size_t)ray * kS;
        R.zq = (v4f)(0.f); R.sq = (v4f)(0.f);
        R.c0 = (v4f)(0.f); R.c1 = (v4f)(0.f); R.c2 = (v4f)(0.f);
        if (act) {
            R.zq = *reinterpret_cast<const v4f*>(z_vals + base + 4 * lane);
            R.sq = *reinterpret_cast<const v4f*>(sigma  + base + 4 * lane);
            const float* rp = rgb + base * 3 + 12 * lane;   // 16B-aligned (48B stride)
            R.c0 = *reinterpret_cast<const v4f*>(rp);
            R.c1 = *reinterpret_cast<const v4f*>(rp + 4);
            R.c2 = *reinterpret_cast<const v4f*>(rp + 8);
        }
        R.dx = rays_d[ray * 3 + 0];
        R.dy = rays_d[ray * 3 + 1];
        R.dz = rays_d[ray * 3 + 2];
    };

    RayRegs A, B;
    B.zq = (v4f)(0.f); B.sq = (v4f)(0.f); B.c0 = (v4f)(0.f);
    B.c1 = (v4f)(0.f); B.c2 = (v4f)(0.f); B.dx = B.dy = B.dz = 0.f;

    load_ray(ray0, A);

    for (int r = 0; r < kRaysPerWave; ++r) {
        const int ray = ray0 + r;
        // prefetch next ray's 5 fat loads BEFORE touching this ray's data
        if (r + 1 < kRaysPerWave) load_ray(ray + 1, B);

        const float nrm = sqrtf(A.dx * A.dx + A.dy * A.dy + A.dz * A.dz);
        const size_t base = (size_t)ray * kS;

        // neighbor's first z (for element 3's dist); idx 191 uses 1e10 instead
        const float znext = wave_shl1(A.zq[0], 0.f);

        const float zv[4] = {A.zq[0], A.zq[1], A.zq[2], A.zq[3]};
        const float sv[4] = {A.sq[0], A.sq[1], A.sq[2], A.sq[3]};
        const float rv[4] = {A.c0[0], A.c0[3], A.c1[2], A.c2[1]};
        const float gv[4] = {A.c0[1], A.c1[0], A.c1[3], A.c2[2]};
        const float bv[4] = {A.c0[2], A.c1[1], A.c2[0], A.c2[3]};

        float alpha[4], om[4];
        #pragma unroll
        for (int j = 0; j < 4; ++j) {
            const int idx = 4 * lane + j;
            float d;
            if (j < 3)              d = zv[j + 1] - zv[j];
            else if (idx < kS - 1)  d = znext - zv[3];
            else                    d = 1e10f;          // last sample (and idle lanes)
            const float dist = d * nrm;
            const float s = sv[j] > 0.f ? sv[j] : 0.f;  // relu; idle lanes -> alpha=0
            const float e = expf(-s * dist);
            alpha[j] = 1.0f - e;
            om[j]    = 1.0f - alpha[j];                 // match reference rounding
        }

        // local inclusive prefix products, then ONE cross-lane scan
        const float q0 = om[0];
        const float q1 = q0 * om[1];
        const float q2 = q1 * om[2];
        const float q3 = q2 * om[3];
        const float incl = scan_mul64(q3);              // idle lanes contribute 1.0
        const float excl = wave_shr1(incl, 1.0f);       // exclusive prefix

        const float trans[4] = {excl, excl * q0, excl * q1, excl * q2};
        float w[4];
        #pragma unroll
        for (int j = 0; j < 4; ++j) w[j] = alpha[j] * trans[j];

        // fat stores: 3 x global_store_dwordx4
        if (act) {
            const size_t o = base + 4 * lane;
            v4f tv = {trans[0], trans[1], trans[2], trans[3]};
            v4f av = {alpha[0], alpha[1], alpha[2], alpha[3]};
            v4f wv = {w[0], w[1], w[2], w[3]};
            *reinterpret_cast<v4f*>(trans_o + o)   = tv;
            *reinterpret_cast<v4f*>(alpha_o + o)   = av;
            *reinterpret_cast<v4f*>(weights_o + o) = wv;
        }

        // per-ray scalars: local 4-sum then one 64-lane DPP reduce each
        float sr = 0.f, sg_ = 0.f, sb = 0.f, sd = 0.f, sw = 0.f;
        #pragma unroll
        for (int j = 0; j < 4; ++j) {
            sr  += w[j] * rv[j];
            sg_ += w[j] * gv[j];
            sb  += w[j] * bv[j];
            sd  += w[j] * zv[j];
            sw  += w[j];
        }
        sr  = red_add64(sr);
        sg_ = red_add64(sg_);
        sb  = red_add64(sb);
        sd  = red_add64(sd);
        sw  = red_add64(sw);

        if (lane == 63) {
            rgb_map[ray * 3 + 0] = sr;
            rgb_map[ray * 3 + 1] = sg_;
            rgb_map[ray * 3 + 2] = sb;
            depth_map[ray] = sd;
            acc_map[ray]   = sw;
            const float q = fmaxf(1e-10f, sd / sw);
            disp_map[ray] = 1.0f / q;
        }

        A = B;   // rotate double buffer (dead copy on last iter; B zero-inited)
    }
}

extern "C" void kernel_launch(void* const* d_in, const int* in_sizes, int n_in,
                              void* d_out, int out_size, void* d_ws, size_t ws_size,
                              hipStream_t stream) {
    const float* rgb    = (const float*)d_in[0];
    const float* sigma  = (const float*)d_in[1];
    const float* z_vals = (const float*)d_in[2];
    const float* rays_d = (const float*)d_in[3];
    float* out = (float*)d_out;

    nerf_render_kernel<<<kBlocks, 256, 0, stream>>>(rgb, sigma, z_vals, rays_d, out);
}